// Round 1
// baseline (166.900 us; speedup 1.0000x reference)
//
#include <hip/hip_runtime.h>

// Problem constants
constexpr int Bn  = 8;
constexpr int Ln  = 2048;
constexpr int En  = 4096;
constexpr int TDn = 768;   // TOKEN_DIM
constexpr int EDn = 256;   // EDGE_DIM
constexpr int Hn  = 128;   // HIDDEN

// ws layout (float offsets)
constexpr int OFF_EDGE = 0;          // B*ED   = 2048  (column sums of edge, scaled by 1/E at use)
constexpr int OFF_T    = 2048;       // B*TD   = 6144  (weighted token sums)
constexpr int OFF_V1   = 8192;       // TD     = 768   (W_fc[:768] @ a1)
constexpr int OFF_S    = 9216;       // B*L    = 16384 (scores, overwritten in-place by softmax probs)
constexpr int OFF_ROW  = 25600;      // B*H    = 1024  (the per-batch output row)
// total 26624 floats = 104 KiB

__global__ void k_zero(float* __restrict__ ws) {
    int i = blockIdx.x * blockDim.x + threadIdx.x;   // 32*256 = 8192 == OFF_V1
    ws[i] = 0.0f;
}

// Per-batch column sums of edge_embedding. grid = B*32, block = 256 (one thread per column).
__global__ void k_edge_sum(const float* __restrict__ edge, float* __restrict__ ws) {
    int b = blockIdx.x >> 5;
    int chunk = blockIdx.x & 31;                     // 32 chunks of 128 rows
    int c = threadIdx.x;
    const float* p = edge + ((size_t)(b * En + chunk * 128)) * EDn + c;
    float acc = 0.f;
    #pragma unroll 4
    for (int e = 0; e < 128; ++e) acc += p[(size_t)e * EDn];
    atomicAdd(&ws[OFF_EDGE + b * EDn + c], acc);
}

// v1[d] = sum_h W_fc[d,h] * a_attn[h]   (only a1 = a_attn[:H] matters)
__global__ void k_v1(const float* __restrict__ W, const float* __restrict__ a,
                     float* __restrict__ ws) {
    __shared__ float a1[Hn];
    if (threadIdx.x < Hn) a1[threadIdx.x] = a[threadIdx.x];
    __syncthreads();
    int d = blockIdx.x * blockDim.x + threadIdx.x;
    if (d >= TDn) return;
    const float* w = W + d * Hn;
    float acc = 0.f;
    #pragma unroll 8
    for (int h = 0; h < Hn; ++h) acc += w[h] * a1[h];
    ws[OFF_V1 + d] = acc;
}

// s[b,l] = token[b,l,:] . v1   — one wave per row, float4 loads, shuffle reduce.
__global__ void k_s(const float* __restrict__ token, float* __restrict__ ws) {
    int wave = threadIdx.x >> 6, lane = threadIdx.x & 63;
    int row = blockIdx.x * 4 + wave;                 // 0 .. B*L-1
    const float4* t4 = (const float4*)token + (size_t)row * (TDn / 4);
    const float4* v4 = (const float4*)(ws + OFF_V1);
    float acc = 0.f;
    #pragma unroll
    for (int j = 0; j < 3; ++j) {
        float4 t = t4[lane + 64 * j];
        float4 v = v4[lane + 64 * j];
        acc += t.x * v.x + t.y * v.y + t.z * v.z + t.w * v.w;
    }
    #pragma unroll
    for (int off = 32; off > 0; off >>= 1)
        acc += __shfl_down(acc, off, 64);
    if (lane == 0) ws[OFF_S + row] = acc;
}

// In-place softmax over L per batch. grid = B, block = 256, 8 elements/thread.
__global__ void k_softmax(float* __restrict__ ws) {
    float* s = ws + OFF_S + blockIdx.x * Ln;
    __shared__ float red[256];
    int tid = threadIdx.x;
    float v[8];
    float m = -1e30f;
    #pragma unroll
    for (int k = 0; k < 8; ++k) { v[k] = s[tid + 256 * k]; m = fmaxf(m, v[k]); }
    red[tid] = m; __syncthreads();
    for (int o = 128; o > 0; o >>= 1) {
        if (tid < o) red[tid] = fmaxf(red[tid], red[tid + o]);
        __syncthreads();
    }
    m = red[0]; __syncthreads();
    float sum = 0.f;
    #pragma unroll
    for (int k = 0; k < 8; ++k) { v[k] = expf(v[k] - m); sum += v[k]; }
    red[tid] = sum; __syncthreads();
    for (int o = 128; o > 0; o >>= 1) {
        if (tid < o) red[tid] += red[tid + o];
        __syncthreads();
    }
    float inv = 1.0f / red[0];
    #pragma unroll
    for (int k = 0; k < 8; ++k) s[tid + 256 * k] = v[k] * inv;
}

// t[b,:] = sum_l p[b,l] * token[b,l,:].  grid = B*32 (64 rows/block), block = 256 (3 cols/thread).
__global__ void k_t(const float* __restrict__ token, float* __restrict__ ws) {
    int b = blockIdx.x >> 5;
    int chunk = blockIdx.x & 31;
    int tid = threadIdx.x;
    const float* p   = ws + OFF_S + b * Ln + chunk * 64;
    const float* tok = token + ((size_t)(b * Ln + chunk * 64)) * TDn;
    float acc0 = 0.f, acc1 = 0.f, acc2 = 0.f;
    for (int l = 0; l < 64; ++l) {
        float w = p[l];
        const float* r = tok + (size_t)l * TDn;
        acc0 += w * r[tid];
        acc1 += w * r[tid + 256];
        acc2 += w * r[tid + 512];
    }
    atomicAdd(&ws[OFF_T + b * TDn + tid],       acc0);
    atomicAdd(&ws[OFF_T + b * TDn + tid + 256], acc1);
    atomicAdd(&ws[OFF_T + b * TDn + tid + 512], acc2);
}

// row[b,h] = t[b,:]·W[:768,h] + (edge_sum[b,:]/E)·W[768:,h]
__global__ void k_row(const float* __restrict__ W, float* __restrict__ ws) {
    int b = blockIdx.x;
    int h = threadIdx.x;                             // 128 threads
    const float* t  = ws + OFF_T + b * TDn;
    const float* es = ws + OFF_EDGE + b * EDn;
    float acc = 0.f;
    for (int d = 0; d < TDn; ++d) acc += t[d] * W[d * Hn + h];
    const float invE = 1.0f / En;
    for (int k = 0; k < EDn; ++k) acc += es[k] * invE * W[(TDn + k) * Hn + h];
    ws[OFF_ROW + b * Hn + h] = acc;
}

// out[b,i,:] = row[b,:] for all i.  float4 stores.
__global__ void k_bcast(const float* __restrict__ ws, float4* __restrict__ out) {
    int idx = blockIdx.x * blockDim.x + threadIdx.x; // 0 .. B*L*H/4 - 1 = 524287
    int b = idx >> 16;                               // / (L*H/4) = 65536
    int q = idx & (Hn / 4 - 1);                      // & 31
    out[idx] = ((const float4*)(ws + OFF_ROW))[b * (Hn / 4) + q];
}

extern "C" void kernel_launch(void* const* d_in, const int* in_sizes, int n_in,
                              void* d_out, int out_size, void* d_ws, size_t ws_size,
                              hipStream_t stream) {
    const float* token = (const float*)d_in[0];
    const float* edge  = (const float*)d_in[1];
    const float* W     = (const float*)d_in[2];
    const float* a     = (const float*)d_in[3];
    // d_in[4] (b_attn) provably cancels in the softmax — unused.
    float* ws  = (float*)d_ws;
    float* out = (float*)d_out;

    k_zero    <<<32,        256, 0, stream>>>(ws);
    k_edge_sum<<<Bn * 32,   256, 0, stream>>>(edge, ws);
    k_v1      <<<3,         256, 0, stream>>>(W, a, ws);
    k_s       <<<Bn * Ln / 4, 256, 0, stream>>>(token, ws);
    k_softmax <<<Bn,        256, 0, stream>>>(ws);
    k_t       <<<Bn * 32,   256, 0, stream>>>(token, ws);
    k_row     <<<Bn,        128, 0, stream>>>(W, ws);
    k_bcast   <<<2048,      256, 0, stream>>>(ws, (float4*)out);
}